// Round 14
// baseline (235.331 us; speedup 1.0000x reference)
//
#include <hip/hip_runtime.h>

#define TT 512
#define DD 16
#define HH 30
#define LL 10
#define C  4                  // timesteps per chunk
#define TCH (TT / C)          // 128 chunks
#define RING 4                // slots per link; sl static via unroll
#define GRP 16                // batches per block = MFMA N
#define BLOCKT (LL * 64)      // 640 threads, wave = layer
#define KPRE 2.885390081777927f   // 2*log2(e)

// LDS strides in halfs: per-(sl,cc) tile = 64 lanes x 8 halfs (contiguous 16B/lane)
#define CC_H   512
#define SL_H   (C * CC_H)     // 2048
#define LINK_H (RING * SL_H)  // 8192

typedef _Float16 f16x8 __attribute__((ext_vector_type(8)));
typedef _Float16 h2    __attribute__((ext_vector_type(2)));
typedef float    f32x4 __attribute__((ext_vector_type(4)));

union U128 { uint4 u; f16x8 h; h2 p[4]; };

// sigma(d) = 1/(exp2(d)+1);  h = 1 - 2*sigma folded into consumer weights/bias.
__device__ __forceinline__ float sigma_e(float d) {
    const float e = __builtin_amdgcn_exp2f(d);
    return __builtin_amdgcn_rcpf(e + 1.0f);
}

// k-position -> natural neuron permutation (MFMA D == next B-own fragment).
__device__ __forceinline__ int nu_of(int k) {
    return 16 * ((k >> 2) & 1) + 4 * (k >> 3) + (k & 3);
}

// Busy-poll (no s_sleep: wake latency = one LDS round-trip; SIMDs are ~40% busy)
__device__ __forceinline__ void wait_ge(unsigned* f, unsigned tgt) {
    while (__hip_atomic_load(f, __ATOMIC_ACQUIRE,
                             __HIP_MEMORY_SCOPE_WORKGROUP) < tgt) {}
}

__global__ __launch_bounds__(BLOCKT) void rnn_pipe(
    const float* __restrict__ x,   const float* __restrict__ wi0,
    const float* __restrict__ wih, const float* __restrict__ whh,
    const float* __restrict__ bih, const float* __restrict__ bhh,
    const float* __restrict__ fcw, const float* __restrict__ fcb,
    float* __restrict__ out)
{
    extern __shared__ __align__(16) _Float16 link[]; // [LL-1][RING][C][512h] = 147456 B
    __shared__ unsigned flg[2 * LL];  // [l]=produced(link l), [LL+l]=consumed(link l-1)

    const int tid  = threadIdx.x;
    const int l    = tid >> 6;        // wave == layer
    const int lane = tid & 63;
    const int n    = lane & 15;       // batch-in-group
    const int qq   = lane >> 4;       // k-slice / D row-group
    const int b0   = blockIdx.x * GRP;

    // ---- A-frags: sigma-folded (-2W), KPRE-prescaled; layer-0 x natural ----
    f16x8 wain[2], waown[2];
    #pragma unroll
    for (int tile = 0; tile < 2; ++tile) {
        const int j = 16 * tile + n;
        #pragma unroll
        for (int i = 0; i < 8; ++i) {
            const int kap = 8 * qq + i;
            const int nu  = nu_of(kap);
            float vi = 0.f, vo = 0.f;
            if (j < HH) {
                if (l == 0) { if (kap < DD) vi =  wi0[j * DD + kap]; }
                else        { if (nu  < HH) vi = -2.f * wih[(l - 1) * 900 + j * HH + nu]; }
                if (nu < HH) vo = -2.f * whh[l * 900 + j * HH + nu];
            }
            wain[tile][i]  = (_Float16)(vi * KPRE);
            waown[tile][i] = (_Float16)(vo * KPRE);
        }
    }
    // ---- bias C-init: KPRE*(b_ih + b_hh + rowsum(Whh) + (l>0 ? rowsum(Wih) : 0))
    f32x4 cb[2];
    #pragma unroll
    for (int tile = 0; tile < 2; ++tile)
        #pragma unroll
        for (int r = 0; r < 4; ++r) {
            const int j2 = 16 * tile + 4 * qq + r;
            float v = 0.f;
            if (j2 < HH) {
                v = bih[l * HH + j2] + bhh[l * HH + j2];
                for (int k = 0; k < HH; ++k) v += whh[l * 900 + j2 * HH + k];
                if (l > 0)
                    for (int k = 0; k < HH; ++k) v += wih[(l - 1) * 900 + j2 * HH + k];
            }
            cb[tile][r] = v * KPRE;
        }
    // ---- FC folded: out = (sum(fcw)+fcb) + sum(-2 fcw * sigma)
    float fcl[8];
    #pragma unroll
    for (int i = 0; i < 8; ++i) {
        const int nu = nu_of(8 * qq + i);
        fcl[i] = (nu < HH) ? -2.f * fcw[nu] : 0.f;
    }
    float fbv = fcb[0];
    for (int k = 0; k < HH; ++k) fbv += fcw[k];

    // LDS link bases (halfs); per-lane 16B slot at lane*8
    _Float16* lin_r = link + (l - 1) * LINK_H + lane * 8;  // valid for l>0
    _Float16* lin_w = link + l * LINK_H + lane * 8;        // valid for l<9

    // recurrent state: sigma-encoded, sigma(h=0) = 0.5
    f16x8 bown;
    #pragma unroll
    for (int i = 0; i < 8; ++i) bown[i] = (_Float16)0.5f;

    if (tid < 2 * LL) flg[tid] = 0u;
    __syncthreads();                  // the only block-wide barrier

    // ---- consumer double-buffer + wave-0 rolling global prefetch ----
    U128 bin[2][C];
    float4 xb[C][2];
    const float4* x4 = (const float4*)x;
    const size_t xbase = (size_t)(b0 + n) * TT * 4;

    if (l == 0) {
        #pragma unroll
        for (int cc = 0; cc < C; ++cc) {          // zero both buffers (qq>=2 stays 0)
            bin[0][cc].u = uint4{0u, 0u, 0u, 0u};
            bin[1][cc].u = uint4{0u, 0u, 0u, 0u};
        }
        if (qq < 2) {
            #pragma unroll
            for (int cc = 0; cc < C; ++cc) {      // chunk 0 -> bin[0]
                const float4 u = x4[xbase + cc * 4 + 2 * qq];
                const float4 v = x4[xbase + cc * 4 + 2 * qq + 1];
                bin[0][cc].p[0] = (h2)__builtin_amdgcn_cvt_pkrtz(u.x, u.y);
                bin[0][cc].p[1] = (h2)__builtin_amdgcn_cvt_pkrtz(u.z, u.w);
                bin[0][cc].p[2] = (h2)__builtin_amdgcn_cvt_pkrtz(v.x, v.y);
                bin[0][cc].p[3] = (h2)__builtin_amdgcn_cvt_pkrtz(v.z, v.w);
                xb[cc][0] = x4[xbase + (C + cc) * 4 + 2 * qq];      // chunk 1 raw
                xb[cc][1] = x4[xbase + (C + cc) * 4 + 2 * qq + 1];
            }
        }
    } else {
        wait_ge(&flg[l - 1], 1u);                 // chunk 0 -> bin[0] (slot 0)
        #pragma unroll
        for (int cc = 0; cc < C; ++cc)
            bin[0][cc].u = *(const uint4*)(lin_r + cc * CC_H);
    }

    for (int pb = 0; pb < TCH; pb += RING) {
        // producer slot-gate, once per group: writing chunks pb..pb+3 reuses
        // slots of chunks pb-4..pb-1 -> need consumer cons >= pb.
        if (l < LL - 1 && pb >= RING)
            wait_ge(&flg[LL + l + 1], (unsigned)pb);

        #pragma unroll
        for (int sl = 0; sl < RING; ++sl) {       // sl literal -> static offsets
            const int pt  = pb + sl;
            const int cur = sl & 1;               // compile-time after unroll
            const int nxt = cur ^ 1;

            // ---- 1. input-side MFMAs from current buffer ----
            f32x4 dp0[C], dp1[C];
            #pragma unroll
            for (int cc = 0; cc < C; ++cc) {
                dp0[cc] = __builtin_amdgcn_mfma_f32_16x16x32_f16(wain[0], bin[cur][cc].h, cb[0], 0, 0, 0);
                dp1[cc] = __builtin_amdgcn_mfma_f32_16x16x32_f16(wain[1], bin[cur][cc].h, cb[1], 0, 0, 0);
            }
            // ---- 2. publish consumption (reads of chunk pt are done) ----
            if (l > 0 && lane == 0)
                __hip_atomic_store(&flg[LL + l], (unsigned)(pt + 1),
                                   __ATOMIC_RELEASE, __HIP_MEMORY_SCOPE_WORKGROUP);

            // ---- 3. prefetch chunk pt+1 into other buffer (latency hides
            //         under the own-chain below) ----
            if (pt + 1 < TCH) {
                if (l == 0) {
                    if (qq < 2) {
                        #pragma unroll
                        for (int cc = 0; cc < C; ++cc) {
                            const float4 u = xb[cc][0], v = xb[cc][1];
                            bin[nxt][cc].p[0] = (h2)__builtin_amdgcn_cvt_pkrtz(u.x, u.y);
                            bin[nxt][cc].p[1] = (h2)__builtin_amdgcn_cvt_pkrtz(u.z, u.w);
                            bin[nxt][cc].p[2] = (h2)__builtin_amdgcn_cvt_pkrtz(v.x, v.y);
                            bin[nxt][cc].p[3] = (h2)__builtin_amdgcn_cvt_pkrtz(v.z, v.w);
                            if (pt + 2 < TCH) {           // chunk pt+2 raw
                                const int tn = (pt + 2) * C + cc;
                                xb[cc][0] = x4[xbase + tn * 4 + 2 * qq];
                                xb[cc][1] = x4[xbase + tn * 4 + 2 * qq + 1];
                            }
                        }
                    }
                } else {
                    wait_ge(&flg[l - 1], (unsigned)(pt + 2));
                    const int nsl = (sl + 1) & 3;
                    #pragma unroll
                    for (int cc = 0; cc < C; ++cc)
                        bin[nxt][cc].u = *(const uint4*)(lin_r + nsl * SL_H + cc * CC_H);
                }
            }

            // ---- 4. serial own-chain: mfma -> sigma -> pack -> ds_write ----
            #pragma unroll
            for (int cc = 0; cc < C; ++cc) {
                const f32x4 d0 = __builtin_amdgcn_mfma_f32_16x16x32_f16(waown[0], bown, dp0[cc], 0, 0, 0);
                const f32x4 d1 = __builtin_amdgcn_mfma_f32_16x16x32_f16(waown[1], bown, dp1[cc], 0, 0, 0);
                U128 uu;
                uu.p[0] = (h2)__builtin_amdgcn_cvt_pkrtz(sigma_e(d0[0]), sigma_e(d0[1]));
                uu.p[1] = (h2)__builtin_amdgcn_cvt_pkrtz(sigma_e(d0[2]), sigma_e(d0[3]));
                uu.p[2] = (h2)__builtin_amdgcn_cvt_pkrtz(sigma_e(d1[0]), sigma_e(d1[1]));
                uu.p[3] = (h2)__builtin_amdgcn_cvt_pkrtz(sigma_e(d1[2]), sigma_e(d1[3]));
                bown = uu.h;
                if (l < LL - 1)
                    *(uint4*)(lin_w + sl * SL_H + cc * CC_H) = uu.u;
            }
            // ---- 5. publish production (release drains our ds_writes) ----
            if (l < LL - 1 && lane == 0)
                __hip_atomic_store(&flg[l], (unsigned)(pt + 1),
                                   __ATOMIC_RELEASE, __HIP_MEMORY_SCOPE_WORKGROUP);
        }
    }

    // ---- FC on sigma_9(T-1): out = (sum fcw + fcb) + sum(-2 fcw * sigma) ----
    if (l == LL - 1) {
        float v = 0.f;
        #pragma unroll
        for (int i = 0; i < 8; ++i) v = fmaf((float)bown[i], fcl[i], v);
        v += __shfl_xor(v, 16);      // combine the four qq k-slices
        v += __shfl_xor(v, 32);
        if (qq == 0) out[b0 + n] = v + fbv;
    }
}

extern "C" void kernel_launch(void* const* d_in, const int* in_sizes, int n_in,
                              void* d_out, int out_size, void* d_ws, size_t ws_size,
                              hipStream_t stream) {
    const float* x   = (const float*)d_in[0];
    const float* wi0 = (const float*)d_in[1];
    const float* wih = (const float*)d_in[2];
    const float* whh = (const float*)d_in[3];
    const float* bih = (const float*)d_in[4];
    const float* bhh = (const float*)d_in[5];
    const float* fcw = (const float*)d_in[6];
    const float* fcb = (const float*)d_in[7];
    float* out = (float*)d_out;

    const size_t lds_bytes = (size_t)(LL - 1) * LINK_H * sizeof(_Float16); // 147456 B
    hipFuncSetAttribute((const void*)rnn_pipe,
                        hipFuncAttributeMaxDynamicSharedMemorySize,
                        (int)lds_bytes);

    rnn_pipe<<<1024 / GRP, BLOCKT, lds_bytes, stream>>>(x, wi0, wih, whh,
                                                        bih, bhh, fcw, fcb, out);
}